// Round 3
// baseline (1397.978 us; speedup 1.0000x reference)
//
#include <hip/hip_runtime.h>
#include <hip/hip_bf16.h>

// CfC cell via three bf16 MFMA GEMMs, 256x256 8-phase schedule (T2 swizzle +
// T3/T4 counted vmcnt + T5 setprio), PERSISTENT: 256 blocks (1/CU), each
// chains TPB tiles with cross-tile pipelined staging (no per-tile drain).

typedef unsigned short u16;
typedef __bf16 bf16x8_t __attribute__((ext_vector_type(8)));
typedef float f32x4_t __attribute__((ext_vector_type(4)));
typedef u16 u16x8_t __attribute__((ext_vector_type(8)));

#define M_TOTAL 131072  // B*T = 128*1024

__device__ __forceinline__ u16 f2bf(float f) {
  union { float f; unsigned u; } v; v.f = f;
  unsigned r = v.u + 0x7FFFu + ((v.u >> 16) & 1u);  // RNE
  return (u16)(r >> 16);
}

__device__ __forceinline__ float fast_tanh(float x) {
  x = fminf(15.f, fmaxf(-15.f, x));
  float e = __expf(2.f * x);
  return (e - 1.f) * __builtin_amdgcn_rcpf(e + 1.f);
}

__device__ __forceinline__ float fast_sigmoid(float x) {
  return __builtin_amdgcn_rcpf(1.f + __expf(-x));
}

__device__ __forceinline__ void gload_lds16(const void* g, void* l) {
  __builtin_amdgcn_global_load_lds(
      (const __attribute__((address_space(1))) unsigned int*)g,
      (__attribute__((address_space(3))) unsigned int*)l,
      16, 0, 0);
}

// ---------------- prep kernels ----------------

__global__ void prep_x(const float* __restrict__ inp, const float* __restrict__ hx,
                       u16* __restrict__ X) {
  const int total = M_TOTAL * 96;
  int stride = gridDim.x * blockDim.x;
  for (int v = blockIdx.x * blockDim.x + threadIdx.x; v < total; v += stride) {
    int m = v / 96; int c = v - m * 96;
    const float* src = (c < 32) ? (inp + (size_t)m * 256 + (c << 3))
                                : (hx + (size_t)m * 512 + ((size_t)(c - 32) << 3));
    f32x4_t a = *(const f32x4_t*)src;
    f32x4_t b = *(const f32x4_t*)(src + 4);
    u16x8_t o;
    o[0]=f2bf(a[0]); o[1]=f2bf(a[1]); o[2]=f2bf(a[2]); o[3]=f2bf(a[3]);
    o[4]=f2bf(b[0]); o[5]=f2bf(b[1]); o[6]=f2bf(b[2]); o[7]=f2bf(b[3]);
    *(u16x8_t*)(X + (size_t)m * 768 + (c << 3)) = o;
  }
}

// all weight transposes + head-interleave + bias interleave in one launch
__global__ void prep_w(const float* __restrict__ W0, const float* __restrict__ W1,
                       const float* __restrict__ Wf1, const float* __restrict__ Wf2,
                       const float* __restrict__ Wta, const float* __restrict__ Wtb,
                       const float* __restrict__ bf1, const float* __restrict__ bf2,
                       const float* __restrict__ bta, const float* __restrict__ btb,
                       u16* __restrict__ W0T, u16* __restrict__ W1T,
                       u16* __restrict__ WhT, float* __restrict__ biasi) {
  int id = blockIdx.x * blockDim.x + threadIdx.x;
  u16x8_t o;
  if (id < 98304) {                       // W0T[n][k] = W0[k][n], K=768
    int n = id / 96, k0 = (id - n * 96) << 3;
#pragma unroll
    for (int i = 0; i < 8; ++i) o[i] = f2bf(W0[(size_t)(k0 + i) * 1024 + n]);
    *(u16x8_t*)(W0T + (size_t)n * 768 + k0) = o;
  } else if (id < 229376) {               // W1T[n][k] = W1[k][n], K=1024
    int id2 = id - 98304; int n = id2 >> 7, k0 = (id2 & 127) << 3;
#pragma unroll
    for (int i = 0; i < 8; ++i) o[i] = f2bf(W1[(size_t)(k0 + i) * 1024 + n]);
    *(u16x8_t*)(W1T + (size_t)n * 1024 + k0) = o;
  } else if (id < 491520) {               // WhT head-interleaved per 16-col block
    int id3 = id - 229376; int head = id3 >> 16; int id4 = id3 & 65535;
    int n = id4 >> 7, k0 = (id4 & 127) << 3;
    const float* W = (head == 0) ? Wf1 : (head == 1) ? Wf2 : (head == 2) ? Wta : Wtb;
#pragma unroll
    for (int i = 0; i < 8; ++i) o[i] = f2bf(W[(size_t)(k0 + i) * 512 + n]);
    int row = ((n >> 4) << 6) + head * 16 + (n & 15);
    *(u16x8_t*)(WhT + (size_t)row * 1024 + k0) = o;
  } else if (id < 492032) {               // interleaved head bias
    int h = id - 491520;
    int base = ((h >> 4) << 6) + (h & 15);
    biasi[base +  0] = bf1[h];
    biasi[base + 16] = bf2[h];
    biasi[base + 32] = bta[h];
    biasi[base + 48] = btb[h];
  }
}

// ---------------- persistent 256x256 8-phase GEMM ----------------
// C = A[M,K] * BT[NI,K]^T, bf16 in / fp32 acc. 512 thr = 8 waves (2Mx4N),
// per-wave 128x64. BK=64 (two 32-col LDS k-slabs). LDS 128 KiB (A@0, B@64K).
// Swizzle st_16x32: stage = linear LDS dest + inverse-swizzled global source.
// Persistent: last iteration of tile t stages tile t+1's k-tiles 0/1.

#define BARX()  do { __builtin_amdgcn_s_barrier(); __builtin_amdgcn_sched_barrier(0); } while(0)
#define LGKM0() do { asm volatile("s_waitcnt lgkmcnt(0)" ::: "memory"); __builtin_amdgcn_sched_barrier(0); } while(0)
#define VMC4()  do { asm volatile("s_waitcnt vmcnt(4)" ::: "memory"); } while(0)

template<int K, int NI, int EPI, int TPB>
__global__ __launch_bounds__(512, 2)
void gemm256(const u16* __restrict__ A, const u16* __restrict__ BT,
             const float* __restrict__ bias, const float* __restrict__ ts,
             void* __restrict__ Cout)
{
  constexpr int NTn = NI / 256;
  constexpr int NITER = K / 128;           // 2 k-tiles (of 64) per iteration
  __shared__ __align__(16) char smem[131072];

  const int tid = threadIdx.x;
  const int w = tid >> 6, l = tid & 63;
  const int wm = w >> 2, wn = w & 3;

  // staging lane constants: chunk c=2w+j (1024B), slab kk=c>>3,
  // rows (c&7)*16+(l>>2), colbyte ((l&3)<<4) ^ ((l>>5)&1)<<5 (inverse swz)
  const int c0 = w * 2, c1 = w * 2 + 1;
  const int kkS0 = c0 >> 3, kkS1 = c1 >> 3;
  const int rS0 = (c0 & 7) * 16 + (l >> 2);
  const int rS1 = (c1 & 7) * 16 + (l >> 2);
  const int cbS = ((l & 3) << 4) ^ (((l >> 5) & 1) << 5);
  const int cA0 = (c0 & 7) * 1024, cA1 = (c1 & 7) * 1024;
  const int laneK = cbS >> 1;

  // fragment read addressing (swizzle applied on read)
  const int colRs = ((l >> 4) * 16) ^ (((l >> 3) & 1) << 5);
  const int aRowB = (wm * 128 + (l & 15)) * 64;
  const int bRowB = 65536 + (wn * 64 + (l & 15)) * 64;

  f32x4_t acc[8][4];
  bf16x8_t af[4][2], b01[2][2], b23[2][2];

#define STAGE_A(d, h, SRC, t) do { \
    gload_lds16((SRC) + (size_t)((h)*128 + rS0) * K + (t)*64 + kkS0*32, \
                smem + (d)*32768 + kkS0*16384 + (h)*8192 + cA0); \
    gload_lds16((SRC) + (size_t)((h)*128 + rS1) * K + (t)*64 + kkS1*32, \
                smem + (d)*32768 + kkS1*16384 + (h)*8192 + cA1); } while(0)

#define STAGE_B(d, h, SRC, t) do { \
    gload_lds16((SRC) + (size_t)((h)*128 + rS0) * K + (t)*64 + kkS0*32, \
                smem + 65536 + (d)*32768 + kkS0*16384 + (h)*8192 + cA0); \
    gload_lds16((SRC) + (size_t)((h)*128 + rS1) * K + (t)*64 + kkS1*32, \
                smem + 65536 + (d)*32768 + kkS1*16384 + (h)*8192 + cA1); } while(0)

#define READ_A(d, mb) do { \
    _Pragma("unroll") for (int mm_ = 0; mm_ < 4; ++mm_) { \
      af[mm_][0] = *(const bf16x8_t*)(smem + (d)*32768 +         aRowB + ((mb)+mm_)*1024 + colRs); \
      af[mm_][1] = *(const bf16x8_t*)(smem + (d)*32768 + 16384 + aRowB + ((mb)+mm_)*1024 + colRs); } } while(0)

#define READ_B(d, breg, nb) do { \
    _Pragma("unroll") for (int nn_ = 0; nn_ < 2; ++nn_) { \
      breg[nn_][0] = *(const bf16x8_t*)(smem + (d)*32768 +         bRowB + ((nb)+nn_)*1024 + colRs); \
      breg[nn_][1] = *(const bf16x8_t*)(smem + (d)*32768 + 16384 + bRowB + ((nb)+nn_)*1024 + colRs); } } while(0)

#define MFMAQ(mb, nb, breg) do { \
    __builtin_amdgcn_s_setprio(1); \
    _Pragma("unroll") for (int kk_ = 0; kk_ < 2; ++kk_) \
      _Pragma("unroll") for (int mm_ = 0; mm_ < 4; ++mm_) \
        _Pragma("unroll") for (int nn_ = 0; nn_ < 2; ++nn_) \
          acc[(mb)+mm_][(nb)+nn_] = __builtin_amdgcn_mfma_f32_16x16x32_bf16( \
              af[mm_][kk_], breg[nn_][kk_], acc[(mb)+mm_][(nb)+nn_], 0, 0, 0); \
    __builtin_amdgcn_s_setprio(0); \
  } while(0)

// one 8-phase iteration; stages t1=2i+1 from aCur, and (T2,T3) from (A2,B2)
#define ITER(ii, A2, B2, T2, T3) do { \
    READ_A(0, 0); READ_B(0, b01, 0); \
    STAGE_A(1, 0, aCur, 2*(ii)+1); \
    BARX(); LGKM0(); MFMAQ(0, 0, b01); BARX(); \
    READ_B(0, b23, 2); \
    STAGE_A(1, 1, aCur, 2*(ii)+1); \
    BARX(); LGKM0(); MFMAQ(0, 2, b23); BARX(); \
    READ_A(0, 4); \
    STAGE_B(0, 0, B2, T2); \
    BARX(); LGKM0(); MFMAQ(4, 0, b01); BARX(); \
    STAGE_B(0, 1, B2, T2); \
    BARX(); MFMAQ(4, 2, b23); \
    VMC4(); BARX(); \
    READ_A(1, 0); READ_B(1, b01, 0); \
    STAGE_A(0, 0, A2, T2); \
    BARX(); LGKM0(); MFMAQ(0, 0, b01); BARX(); \
    READ_B(1, b23, 2); \
    STAGE_A(0, 1, A2, T2); \
    BARX(); LGKM0(); MFMAQ(0, 2, b23); BARX(); \
    READ_A(1, 4); \
    STAGE_B(1, 0, B2, T3); \
    BARX(); LGKM0(); MFMAQ(4, 0, b01); BARX(); \
    STAGE_B(1, 1, B2, T3); \
    BARX(); MFMAQ(4, 2, b23); \
    VMC4(); BARX(); \
  } while(0)

  const int tile0 = blockIdx.x * TPB;

  // prologue: first tile's buf0 (k0, A+B) + buf1.B (k1)
  {
    const int mt0 = tile0 / NTn, nt0 = tile0 % NTn;
    const u16* a0 = A + (size_t)(mt0 * 256) * K + laneK;
    const u16* b0 = BT + (size_t)(nt0 * 256) * K + laneK;
    STAGE_A(0, 0, a0, 0); STAGE_A(0, 1, a0, 0);
    STAGE_B(0, 0, b0, 0); STAGE_B(0, 1, b0, 0);
    STAGE_B(1, 0, b0, 1); STAGE_B(1, 1, b0, 1);
    VMC4(); BARX();
  }

#pragma unroll 1
  for (int tt = 0; tt < TPB; ++tt) {
    const int tcur = tile0 + tt;
    const int tnxt = (tt + 1 < TPB) ? tcur + 1 : tcur;  // wrap: restage self (L2-hot)
    const int tileM = (tcur / NTn) * 256, tileN = (tcur % NTn) * 256;
    const u16* aCur = A + (size_t)tileM * K + laneK;
    const u16* bCur = BT + (size_t)tileN * K + laneK;
    const u16* aNxt = A + (size_t)((tnxt / NTn) * 256) * K + laneK;
    const u16* bNxt = BT + (size_t)((tnxt % NTn) * 256) * K + laneK;

    const int colBase = tileN + wn * 64 + (l & 15);
    float bv[4];
    bv[0] = bias[colBase];      bv[1] = bias[colBase + 16];
    bv[2] = bias[colBase + 32]; bv[3] = bias[colBase + 48];

#pragma unroll
    for (int i = 0; i < 8; ++i)
#pragma unroll
      for (int j = 0; j < 4; ++j) acc[i][j] = f32x4_t{0.f, 0.f, 0.f, 0.f};

#pragma unroll 1
    for (int i = 0; i < NITER - 1; ++i) ITER(i, aCur, bCur, 2 * i + 2, 2 * i + 3);
    ITER(NITER - 1, aNxt, bNxt, 0, 1);   // cross-tile: stage next tile k0/k1

    // epilogue (no LDS use — next tile's stages are in flight into LDS)
    // C/D layout: col = lane&15, row = (lane>>4)*4 + reg (m89-verified)
    if constexpr (EPI == 0) {
      u16* C = (u16*)Cout;
      const int rowB = tileM + wm * 128 + ((l >> 4) << 2);
#pragma unroll
      for (int m = 0; m < 8; ++m)
#pragma unroll
        for (int nn = 0; nn < 4; ++nn)
#pragma unroll
          for (int j = 0; j < 4; ++j) {
            float v = acc[m][nn][j] + bv[nn];
            float t = 1.7159f * fast_tanh(0.666f * v);
            C[(size_t)(rowB + m * 16 + j) * NI + colBase + nn * 16] = f2bf(t);
          }
    } else {
      const int hg = ((tileN + wn * 64) >> 6) * 16 + (l & 15);
      float* out = (float*)Cout;
#pragma unroll
      for (int m = 0; m < 8; ++m)
#pragma unroll
        for (int j = 0; j < 4; ++j) {
          const int rl = wm * 128 + m * 16 + ((l >> 4) << 2) + j;
          const float tsv = ts[tileM + rl];   // L1 broadcast hit
          float ff1 = fast_tanh(acc[m][0][j] + bv[0]);
          float ff2 = fast_tanh(acc[m][1][j] + bv[1]);
          float s = fast_sigmoid((acc[m][2][j] + bv[2]) * tsv + (acc[m][3][j] + bv[3]));
          out[(size_t)(tileM + rl) * 512 + hg] = ff1 + s * (ff2 - ff1);
        }
    }
  }

  asm volatile("s_waitcnt vmcnt(0)" ::: "memory");  // drain wrapped stages before exit

#undef STAGE_A
#undef STAGE_B
#undef READ_A
#undef READ_B
#undef MFMAQ
#undef ITER
}

// ---------------- launch ----------------

extern "C" void kernel_launch(void* const* d_in, const int* in_sizes, int n_in,
                              void* d_out, int out_size, void* d_ws, size_t ws_size,
                              hipStream_t stream) {
  const float* input = (const float*)d_in[0];
  const float* hx    = (const float*)d_in[1];
  const float* ts    = (const float*)d_in[2];
  const float* W0    = (const float*)d_in[3];
  const float* b0    = (const float*)d_in[4];
  const float* W1    = (const float*)d_in[5];
  const float* b1    = (const float*)d_in[6];
  const float* Wff1  = (const float*)d_in[7];
  const float* bff1  = (const float*)d_in[8];
  const float* Wff2  = (const float*)d_in[9];
  const float* bff2  = (const float*)d_in[10];
  const float* Wta   = (const float*)d_in[11];
  const float* bta   = (const float*)d_in[12];
  const float* Wtb   = (const float*)d_in[13];
  const float* btb   = (const float*)d_in[14];

  const size_t WS_NEEDED = 544743424ull;
  if (ws_size < WS_NEEDED) return;
  char* ws = (char*)d_ws;
  u16* Xcat = (u16*)(ws);                      // [M,768] bf16, reused as X2 [M,1024]
  u16* X2   = (u16*)(ws);
  u16* X1   = (u16*)(ws + 268435456ull);       // [M,1024] bf16
  u16* W0T  = (u16*)(ws + 536870912ull);       // [1024][768]
  u16* W1T  = (u16*)(ws + 538443776ull);       // [1024][1024]
  u16* WhT  = (u16*)(ws + 540540928ull);       // [2048][1024] head-interleaved
  float* biasi = (float*)(ws + 544735232ull);  // [2048]

  prep_x<<<2048, 256, 0, stream>>>(input, hx, Xcat);
  prep_w<<<1922, 256, 0, stream>>>(W0, W1, Wff1, Wff2, Wta, Wtb,
                                   bff1, bff2, bta, btb, W0T, W1T, WhT, biasi);

  gemm256<768, 1024, 0, 8><<<256, 512, 0, stream>>>(Xcat, W0T, b0, nullptr, X1);
  gemm256<1024, 1024, 0, 8><<<256, 512, 0, stream>>>(X1, W1T, b1, nullptr, X2);
  gemm256<1024, 2048, 1, 16><<<256, 512, 0, stream>>>(X2, WhT, biasi, ts, d_out);
}

// Round 4
// 1256.171 us; speedup vs baseline: 1.1129x; 1.1129x over previous
//
#include <hip/hip_runtime.h>
#include <hip/hip_bf16.h>

// CfC cell via three bf16 MFMA GEMMs, 256x256 8-phase schedule (T2 swizzle +
// T3/T4 counted vmcnt + T5 setprio), PERSISTENT (1 block/CU) with round-2
// L2-friendly tile ordering: block (xcd=b&7, slot=b>>3) walks
// tile = xcd*(NWG/8) + slot + 32*tt  -> per-XCD contiguous 32-tile windows
// (A-panels L2-shared 8-ways, B L2-resident, fixed per-block B-column).

typedef unsigned short u16;
typedef __bf16 bf16x8_t __attribute__((ext_vector_type(8)));
typedef float f32x4_t __attribute__((ext_vector_type(4)));
typedef u16 u16x8_t __attribute__((ext_vector_type(8)));

#define M_TOTAL 131072  // B*T = 128*1024

__device__ __forceinline__ u16 f2bf(float f) {
  union { float f; unsigned u; } v; v.f = f;
  unsigned r = v.u + 0x7FFFu + ((v.u >> 16) & 1u);  // RNE
  return (u16)(r >> 16);
}

__device__ __forceinline__ float fast_tanh(float x) {
  x = fminf(15.f, fmaxf(-15.f, x));
  float e = __expf(2.f * x);
  return (e - 1.f) * __builtin_amdgcn_rcpf(e + 1.f);
}

__device__ __forceinline__ float fast_sigmoid(float x) {
  return __builtin_amdgcn_rcpf(1.f + __expf(-x));
}

__device__ __forceinline__ void gload_lds16(const void* g, void* l) {
  __builtin_amdgcn_global_load_lds(
      (const __attribute__((address_space(1))) unsigned int*)g,
      (__attribute__((address_space(3))) unsigned int*)l,
      16, 0, 0);
}

// ---------------- prep kernels ----------------

__global__ void prep_x(const float* __restrict__ inp, const float* __restrict__ hx,
                       u16* __restrict__ X) {
  const int total = M_TOTAL * 96;
  int stride = gridDim.x * blockDim.x;
  for (int v = blockIdx.x * blockDim.x + threadIdx.x; v < total; v += stride) {
    int m = v / 96; int c = v - m * 96;
    const float* src = (c < 32) ? (inp + (size_t)m * 256 + (c << 3))
                                : (hx + (size_t)m * 512 + ((size_t)(c - 32) << 3));
    f32x4_t a = *(const f32x4_t*)src;
    f32x4_t b = *(const f32x4_t*)(src + 4);
    u16x8_t o;
    o[0]=f2bf(a[0]); o[1]=f2bf(a[1]); o[2]=f2bf(a[2]); o[3]=f2bf(a[3]);
    o[4]=f2bf(b[0]); o[5]=f2bf(b[1]); o[6]=f2bf(b[2]); o[7]=f2bf(b[3]);
    *(u16x8_t*)(X + (size_t)m * 768 + (c << 3)) = o;
  }
}

// all weight transposes + head-interleave + bias interleave in one launch
__global__ void prep_w(const float* __restrict__ W0, const float* __restrict__ W1,
                       const float* __restrict__ Wf1, const float* __restrict__ Wf2,
                       const float* __restrict__ Wta, const float* __restrict__ Wtb,
                       const float* __restrict__ bf1, const float* __restrict__ bf2,
                       const float* __restrict__ bta, const float* __restrict__ btb,
                       u16* __restrict__ W0T, u16* __restrict__ W1T,
                       u16* __restrict__ WhT, float* __restrict__ biasi) {
  int id = blockIdx.x * blockDim.x + threadIdx.x;
  u16x8_t o;
  if (id < 98304) {                       // W0T[n][k] = W0[k][n], K=768
    int n = id / 96, k0 = (id - n * 96) << 3;
#pragma unroll
    for (int i = 0; i < 8; ++i) o[i] = f2bf(W0[(size_t)(k0 + i) * 1024 + n]);
    *(u16x8_t*)(W0T + (size_t)n * 768 + k0) = o;
  } else if (id < 229376) {               // W1T[n][k] = W1[k][n], K=1024
    int id2 = id - 98304; int n = id2 >> 7, k0 = (id2 & 127) << 3;
#pragma unroll
    for (int i = 0; i < 8; ++i) o[i] = f2bf(W1[(size_t)(k0 + i) * 1024 + n]);
    *(u16x8_t*)(W1T + (size_t)n * 1024 + k0) = o;
  } else if (id < 491520) {               // WhT head-interleaved per 16-col block
    int id3 = id - 229376; int head = id3 >> 16; int id4 = id3 & 65535;
    int n = id4 >> 7, k0 = (id4 & 127) << 3;
    const float* W = (head == 0) ? Wf1 : (head == 1) ? Wf2 : (head == 2) ? Wta : Wtb;
#pragma unroll
    for (int i = 0; i < 8; ++i) o[i] = f2bf(W[(size_t)(k0 + i) * 512 + n]);
    int row = ((n >> 4) << 6) + head * 16 + (n & 15);
    *(u16x8_t*)(WhT + (size_t)row * 1024 + k0) = o;
  } else if (id < 492032) {               // interleaved head bias
    int h = id - 491520;
    int base = ((h >> 4) << 6) + (h & 15);
    biasi[base +  0] = bf1[h];
    biasi[base + 16] = bf2[h];
    biasi[base + 32] = bta[h];
    biasi[base + 48] = btb[h];
  }
}

// ---------------- persistent 256x256 8-phase GEMM ----------------
// C = A[M,K] * BT[NI,K]^T, bf16 in / fp32 acc. 512 thr = 8 waves (2Mx4N),
// per-wave 128x64. BK=64 (two 32-col LDS k-slabs). LDS 128 KiB (A@0, B@64K).
// Swizzle st_16x32: stage = linear LDS dest + inverse-swizzled global source.
// Persistent: last iteration of tile t stages tile t+32's k-tiles 0/1.

#define BARX()  do { __builtin_amdgcn_s_barrier(); __builtin_amdgcn_sched_barrier(0); } while(0)
#define LGKM0() do { asm volatile("s_waitcnt lgkmcnt(0)" ::: "memory"); __builtin_amdgcn_sched_barrier(0); } while(0)
#define VMC4()  do { asm volatile("s_waitcnt vmcnt(4)" ::: "memory"); } while(0)

template<int K, int NI, int EPI, int TPB>
__global__ __launch_bounds__(512, 2)
void gemm256(const u16* __restrict__ A, const u16* __restrict__ BT,
             const float* __restrict__ bias, const float* __restrict__ ts,
             void* __restrict__ Cout)
{
  constexpr int NTn = NI / 256;
  constexpr int NITER = K / 128;           // 2 k-tiles (of 64) per iteration
  constexpr int NWG = (M_TOTAL / 256) * NTn;
  constexpr int RPX = NWG / 8;             // tiles per XCD
  __shared__ __align__(16) char smem[131072];

  const int tid = threadIdx.x;
  const int w = tid >> 6, l = tid & 63;
  const int wm = w >> 2, wn = w & 3;

  // staging lane constants: chunk c=2w+j (1024B), slab kk=c>>3,
  // rows (c&7)*16+(l>>2), colbyte ((l&3)<<4) ^ ((l>>5)&1)<<5 (inverse swz)
  const int c0 = w * 2, c1 = w * 2 + 1;
  const int kkS0 = c0 >> 3, kkS1 = c1 >> 3;
  const int rS0 = (c0 & 7) * 16 + (l >> 2);
  const int rS1 = (c1 & 7) * 16 + (l >> 2);
  const int cbS = ((l & 3) << 4) ^ (((l >> 5) & 1) << 5);
  const int cA0 = (c0 & 7) * 1024, cA1 = (c1 & 7) * 1024;
  const int laneK = cbS >> 1;

  // fragment read addressing (swizzle applied on read)
  const int colRs = ((l >> 4) * 16) ^ (((l >> 3) & 1) << 5);
  const int aRowB = (wm * 128 + (l & 15)) * 64;
  const int bRowB = 65536 + (wn * 64 + (l & 15)) * 64;

  f32x4_t acc[8][4];
  bf16x8_t af[4][2], b01[2][2], b23[2][2];

#define STAGE_A(d, h, SRC, t) do { \
    gload_lds16((SRC) + (size_t)((h)*128 + rS0) * K + (t)*64 + kkS0*32, \
                smem + (d)*32768 + kkS0*16384 + (h)*8192 + cA0); \
    gload_lds16((SRC) + (size_t)((h)*128 + rS1) * K + (t)*64 + kkS1*32, \
                smem + (d)*32768 + kkS1*16384 + (h)*8192 + cA1); } while(0)

#define STAGE_B(d, h, SRC, t) do { \
    gload_lds16((SRC) + (size_t)((h)*128 + rS0) * K + (t)*64 + kkS0*32, \
                smem + 65536 + (d)*32768 + kkS0*16384 + (h)*8192 + cA0); \
    gload_lds16((SRC) + (size_t)((h)*128 + rS1) * K + (t)*64 + kkS1*32, \
                smem + 65536 + (d)*32768 + kkS1*16384 + (h)*8192 + cA1); } while(0)

#define READ_A(d, mb) do { \
    _Pragma("unroll") for (int mm_ = 0; mm_ < 4; ++mm_) { \
      af[mm_][0] = *(const bf16x8_t*)(smem + (d)*32768 +         aRowB + ((mb)+mm_)*1024 + colRs); \
      af[mm_][1] = *(const bf16x8_t*)(smem + (d)*32768 + 16384 + aRowB + ((mb)+mm_)*1024 + colRs); } } while(0)

#define READ_B(d, breg, nb) do { \
    _Pragma("unroll") for (int nn_ = 0; nn_ < 2; ++nn_) { \
      breg[nn_][0] = *(const bf16x8_t*)(smem + (d)*32768 +         bRowB + ((nb)+nn_)*1024 + colRs); \
      breg[nn_][1] = *(const bf16x8_t*)(smem + (d)*32768 + 16384 + bRowB + ((nb)+nn_)*1024 + colRs); } } while(0)

#define MFMAQ(mb, nb, breg) do { \
    __builtin_amdgcn_s_setprio(1); \
    _Pragma("unroll") for (int kk_ = 0; kk_ < 2; ++kk_) \
      _Pragma("unroll") for (int mm_ = 0; mm_ < 4; ++mm_) \
        _Pragma("unroll") for (int nn_ = 0; nn_ < 2; ++nn_) \
          acc[(mb)+mm_][(nb)+nn_] = __builtin_amdgcn_mfma_f32_16x16x32_bf16( \
              af[mm_][kk_], breg[nn_][kk_], acc[(mb)+mm_][(nb)+nn_], 0, 0, 0); \
    __builtin_amdgcn_s_setprio(0); \
  } while(0)

// one 8-phase iteration; stages t1=2i+1 from aCur, and (T2,T3) from (A2,B2)
#define ITER(ii, A2, B2, T2, T3) do { \
    READ_A(0, 0); READ_B(0, b01, 0); \
    STAGE_A(1, 0, aCur, 2*(ii)+1); \
    BARX(); LGKM0(); MFMAQ(0, 0, b01); BARX(); \
    READ_B(0, b23, 2); \
    STAGE_A(1, 1, aCur, 2*(ii)+1); \
    BARX(); LGKM0(); MFMAQ(0, 2, b23); BARX(); \
    READ_A(0, 4); \
    STAGE_B(0, 0, B2, T2); \
    BARX(); LGKM0(); MFMAQ(4, 0, b01); BARX(); \
    STAGE_B(0, 1, B2, T2); \
    BARX(); MFMAQ(4, 2, b23); \
    VMC4(); BARX(); \
    READ_A(1, 0); READ_B(1, b01, 0); \
    STAGE_A(0, 0, A2, T2); \
    BARX(); LGKM0(); MFMAQ(0, 0, b01); BARX(); \
    READ_B(1, b23, 2); \
    STAGE_A(0, 1, A2, T2); \
    BARX(); LGKM0(); MFMAQ(0, 2, b23); BARX(); \
    READ_A(1, 4); \
    STAGE_B(1, 0, B2, T3); \
    BARX(); LGKM0(); MFMAQ(4, 0, b01); BARX(); \
    STAGE_B(1, 1, B2, T3); \
    BARX(); MFMAQ(4, 2, b23); \
    VMC4(); BARX(); \
  } while(0)

  // tile sequence: per-XCD contiguous window, stride 32 per step
  const int xcd = blockIdx.x & 7, slot = blockIdx.x >> 3;
  const int tileBase = xcd * RPX + slot;

  // prologue: first tile's buf0 (k0, A+B) + buf1.B (k1)
  {
    const int t0 = tileBase;
    const u16* a0 = A + (size_t)((t0 / NTn) * 256) * K + laneK;
    const u16* b0 = BT + (size_t)((t0 % NTn) * 256) * K + laneK;
    STAGE_A(0, 0, a0, 0); STAGE_A(0, 1, a0, 0);
    STAGE_B(0, 0, b0, 0); STAGE_B(0, 1, b0, 0);
    STAGE_B(1, 0, b0, 1); STAGE_B(1, 1, b0, 1);
    VMC4(); BARX();
  }

#pragma unroll 1
  for (int tt = 0; tt < TPB; ++tt) {
    const int tcur = tileBase + 32 * tt;
    const int tnxt = (tt + 1 < TPB) ? tcur + 32 : tcur;  // wrap: restage self (L2-hot)
    const int tileM = (tcur / NTn) * 256, tileN = (tcur % NTn) * 256;
    const u16* aCur = A + (size_t)tileM * K + laneK;
    const u16* bCur = BT + (size_t)tileN * K + laneK;
    const u16* aNxt = A + (size_t)((tnxt / NTn) * 256) * K + laneK;
    const u16* bNxt = BT + (size_t)((tnxt % NTn) * 256) * K + laneK;

    const int colBase = tileN + wn * 64 + (l & 15);
    float bv[4];
    bv[0] = bias[colBase];      bv[1] = bias[colBase + 16];
    bv[2] = bias[colBase + 32]; bv[3] = bias[colBase + 48];

#pragma unroll
    for (int i = 0; i < 8; ++i)
#pragma unroll
      for (int j = 0; j < 4; ++j) acc[i][j] = f32x4_t{0.f, 0.f, 0.f, 0.f};

#pragma unroll 1
    for (int i = 0; i < NITER - 1; ++i) ITER(i, aCur, bCur, 2 * i + 2, 2 * i + 3);
    ITER(NITER - 1, aNxt, bNxt, 0, 1);   // cross-tile: stage next tile k0/k1

    // epilogue (no LDS use — next tile's stages are in flight into LDS)
    // C/D layout: col = lane&15, row = (lane>>4)*4 + reg (m89-verified)
    if constexpr (EPI == 0) {
      u16* C = (u16*)Cout;
      const int rowB = tileM + wm * 128 + ((l >> 4) << 2);
#pragma unroll
      for (int m = 0; m < 8; ++m)
#pragma unroll
        for (int nn = 0; nn < 4; ++nn)
#pragma unroll
          for (int j = 0; j < 4; ++j) {
            float v = acc[m][nn][j] + bv[nn];
            float t = 1.7159f * fast_tanh(0.666f * v);
            C[(size_t)(rowB + m * 16 + j) * NI + colBase + nn * 16] = f2bf(t);
          }
    } else {
      const int hg = ((tileN + wn * 64) >> 6) * 16 + (l & 15);
      float* out = (float*)Cout;
#pragma unroll
      for (int m = 0; m < 8; ++m)
#pragma unroll
        for (int j = 0; j < 4; ++j) {
          const int rl = wm * 128 + m * 16 + ((l >> 4) << 2) + j;
          const float tsv = ts[tileM + rl];   // L1 broadcast hit
          float ff1 = fast_tanh(acc[m][0][j] + bv[0]);
          float ff2 = fast_tanh(acc[m][1][j] + bv[1]);
          float s = fast_sigmoid((acc[m][2][j] + bv[2]) * tsv + (acc[m][3][j] + bv[3]));
          out[(size_t)(tileM + rl) * 512 + hg] = ff1 + s * (ff2 - ff1);
        }
    }
  }

  asm volatile("s_waitcnt vmcnt(0)" ::: "memory");  // drain wrapped stages before exit

#undef STAGE_A
#undef STAGE_B
#undef READ_A
#undef READ_B
#undef MFMAQ
#undef ITER
}

// ---------------- launch ----------------

extern "C" void kernel_launch(void* const* d_in, const int* in_sizes, int n_in,
                              void* d_out, int out_size, void* d_ws, size_t ws_size,
                              hipStream_t stream) {
  const float* input = (const float*)d_in[0];
  const float* hx    = (const float*)d_in[1];
  const float* ts    = (const float*)d_in[2];
  const float* W0    = (const float*)d_in[3];
  const float* b0    = (const float*)d_in[4];
  const float* W1    = (const float*)d_in[5];
  const float* b1    = (const float*)d_in[6];
  const float* Wff1  = (const float*)d_in[7];
  const float* bff1  = (const float*)d_in[8];
  const float* Wff2  = (const float*)d_in[9];
  const float* bff2  = (const float*)d_in[10];
  const float* Wta   = (const float*)d_in[11];
  const float* bta   = (const float*)d_in[12];
  const float* Wtb   = (const float*)d_in[13];
  const float* btb   = (const float*)d_in[14];

  const size_t WS_NEEDED = 544743424ull;
  if (ws_size < WS_NEEDED) return;
  char* ws = (char*)d_ws;
  u16* Xcat = (u16*)(ws);                      // [M,768] bf16, reused as X2 [M,1024]
  u16* X2   = (u16*)(ws);
  u16* X1   = (u16*)(ws + 268435456ull);       // [M,1024] bf16
  u16* W0T  = (u16*)(ws + 536870912ull);       // [1024][768]
  u16* W1T  = (u16*)(ws + 538443776ull);       // [1024][1024]
  u16* WhT  = (u16*)(ws + 540540928ull);       // [2048][1024] head-interleaved
  float* biasi = (float*)(ws + 544735232ull);  // [2048]

  prep_x<<<2048, 256, 0, stream>>>(input, hx, Xcat);
  prep_w<<<1922, 256, 0, stream>>>(W0, W1, Wff1, Wff2, Wta, Wtb,
                                   bff1, bff2, bta, btb, W0T, W1T, WhT, biasi);

  gemm256<768, 1024, 0, 8><<<256, 512, 0, stream>>>(Xcat, W0T, b0, nullptr, X1);
  gemm256<1024, 1024, 0, 8><<<256, 512, 0, stream>>>(X1, W1T, b1, nullptr, X2);
  gemm256<1024, 2048, 1, 16><<<256, 512, 0, stream>>>(X2, WhT, biasi, ts, d_out);
}

// Round 5
// 1243.036 us; speedup vs baseline: 1.1246x; 1.0106x over previous
//
#include <hip/hip_runtime.h>
#include <hip/hip_bf16.h>

// CfC cell via three bf16 MFMA GEMMs. 256x256 tile, 512 thr = 8 waves (2Mx4N),
// 4-slab rotating K-pipeline (32-col slabs), depth-3 prefetch via counted
// vmcnt(8), ONE barrier per 32-k step, st_16x32 LDS swizzle, setprio MFMA.

typedef unsigned short u16;
typedef __bf16 bf16x8_t __attribute__((ext_vector_type(8)));
typedef float f32x4_t __attribute__((ext_vector_type(4)));
typedef u16 u16x8_t __attribute__((ext_vector_type(8)));

#define M_TOTAL 131072  // B*T = 128*1024

__device__ __forceinline__ u16 f2bf(float f) {
  union { float f; unsigned u; } v; v.f = f;
  unsigned r = v.u + 0x7FFFu + ((v.u >> 16) & 1u);  // RNE
  return (u16)(r >> 16);
}

__device__ __forceinline__ float fast_tanh(float x) {
  x = fminf(15.f, fmaxf(-15.f, x));
  float e = __expf(2.f * x);
  return (e - 1.f) * __builtin_amdgcn_rcpf(e + 1.f);
}

__device__ __forceinline__ float fast_sigmoid(float x) {
  return __builtin_amdgcn_rcpf(1.f + __expf(-x));
}

__device__ __forceinline__ void gload_lds16(const void* g, void* l) {
  __builtin_amdgcn_global_load_lds(
      (const __attribute__((address_space(1))) unsigned int*)g,
      (__attribute__((address_space(3))) unsigned int*)l,
      16, 0, 0);
}

// ---------------- prep kernels ----------------

__global__ void prep_x(const float* __restrict__ inp, const float* __restrict__ hx,
                       u16* __restrict__ X) {
  const int total = M_TOTAL * 96;
  int stride = gridDim.x * blockDim.x;
  for (int v = blockIdx.x * blockDim.x + threadIdx.x; v < total; v += stride) {
    int m = v / 96; int c = v - m * 96;
    const float* src = (c < 32) ? (inp + (size_t)m * 256 + (c << 3))
                                : (hx + (size_t)m * 512 + ((size_t)(c - 32) << 3));
    f32x4_t a = *(const f32x4_t*)src;
    f32x4_t b = *(const f32x4_t*)(src + 4);
    u16x8_t o;
    o[0]=f2bf(a[0]); o[1]=f2bf(a[1]); o[2]=f2bf(a[2]); o[3]=f2bf(a[3]);
    o[4]=f2bf(b[0]); o[5]=f2bf(b[1]); o[6]=f2bf(b[2]); o[7]=f2bf(b[3]);
    *(u16x8_t*)(X + (size_t)m * 768 + (c << 3)) = o;
  }
}

// all weight transposes + head-interleave + bias interleave in one launch
__global__ void prep_w(const float* __restrict__ W0, const float* __restrict__ W1,
                       const float* __restrict__ Wf1, const float* __restrict__ Wf2,
                       const float* __restrict__ Wta, const float* __restrict__ Wtb,
                       const float* __restrict__ bf1, const float* __restrict__ bf2,
                       const float* __restrict__ bta, const float* __restrict__ btb,
                       u16* __restrict__ W0T, u16* __restrict__ W1T,
                       u16* __restrict__ WhT, float* __restrict__ biasi) {
  int id = blockIdx.x * blockDim.x + threadIdx.x;
  u16x8_t o;
  if (id < 98304) {                       // W0T[n][k] = W0[k][n], K=768
    int n = id / 96, k0 = (id - n * 96) << 3;
#pragma unroll
    for (int i = 0; i < 8; ++i) o[i] = f2bf(W0[(size_t)(k0 + i) * 1024 + n]);
    *(u16x8_t*)(W0T + (size_t)n * 768 + k0) = o;
  } else if (id < 229376) {               // W1T[n][k] = W1[k][n], K=1024
    int id2 = id - 98304; int n = id2 >> 7, k0 = (id2 & 127) << 3;
#pragma unroll
    for (int i = 0; i < 8; ++i) o[i] = f2bf(W1[(size_t)(k0 + i) * 1024 + n]);
    *(u16x8_t*)(W1T + (size_t)n * 1024 + k0) = o;
  } else if (id < 491520) {               // WhT head-interleaved per 16-col block
    int id3 = id - 229376; int head = id3 >> 16; int id4 = id3 & 65535;
    int n = id4 >> 7, k0 = (id4 & 127) << 3;
    const float* W = (head == 0) ? Wf1 : (head == 1) ? Wf2 : (head == 2) ? Wta : Wtb;
#pragma unroll
    for (int i = 0; i < 8; ++i) o[i] = f2bf(W[(size_t)(k0 + i) * 512 + n]);
    int row = ((n >> 4) << 6) + head * 16 + (n & 15);
    *(u16x8_t*)(WhT + (size_t)row * 1024 + k0) = o;
  } else if (id < 492032) {               // interleaved head bias
    int h = id - 491520;
    int base = ((h >> 4) << 6) + (h & 15);
    biasi[base +  0] = bf1[h];
    biasi[base + 16] = bf2[h];
    biasi[base + 32] = bta[h];
    biasi[base + 48] = btb[h];
  }
}

// ---------------- 256x256 GEMM, 4-slab rotating pipeline ----------------
// C = A[M,K] * BT[NI,K]^T, bf16 in / fp32 acc.
// LDS: A slabs [4][256][32]bf16 at 0 (64K), B slabs at 65536 (64K).
// Slab = 16KB = 16 chunks of 1024B; wave w stages chunks 2w,2w+1
// (rows 32w..32w+31). st_16x32 swizzle: stage = linear LDS dest +
// inverse-swizzled global col; read applies the same XOR.
// Step i: vmcnt(8) [slab i resident, i+1/i+2 in flight] -> barrier ->
// stage slab (i+3) -> 12x ds_read_b128 -> lgkmcnt(0) -> 32 MFMA.

#define BARX()  do { __builtin_amdgcn_s_barrier(); __builtin_amdgcn_sched_barrier(0); } while(0)
#define LGKM0() do { asm volatile("s_waitcnt lgkmcnt(0)" ::: "memory"); __builtin_amdgcn_sched_barrier(0); } while(0)
#define WAITVM(n) do { asm volatile("s_waitcnt vmcnt(" #n ")" ::: "memory"); __builtin_amdgcn_sched_barrier(0); } while(0)

template<int K, int NI, int EPI>
__global__ __launch_bounds__(512, 2)
void gemm256(const u16* __restrict__ A, const u16* __restrict__ BT,
             const float* __restrict__ bias, const float* __restrict__ ts,
             void* __restrict__ Cout)
{
  constexpr int NTn = NI / 256;
  constexpr int NT = K / 32;               // k-steps (slab = 32 cols)
  constexpr int NWG = (M_TOTAL / 256) * NTn;
  __shared__ __align__(16) char smem[131072];

  const int bid0 = blockIdx.x;
  const int bid = (bid0 & 7) * (NWG >> 3) + (bid0 >> 3);   // XCD swizzle
  const int mt = bid / NTn, nt = bid % NTn;
  const int tileM = mt * 256, tileN = nt * 256;

  const int tid = threadIdx.x;
  const int w = tid >> 6, l = tid & 63;
  const int wm = w >> 2, wn = w & 3;

  // staging lane constants (inverse-swizzled global col)
  const int cbS = ((l & 3) << 4) ^ (((l >> 5) & 1) << 5);
  const int laneK = cbS >> 1;
  const int rA = 32 * w + (l >> 2);
  const u16* aS0 = A + (size_t)(tileM + rA) * K + laneK;
  const u16* aS1 = aS0 + (size_t)16 * K;
  const u16* bS0 = BT + (size_t)(tileN + rA) * K + laneK;
  const u16* bS1 = bS0 + (size_t)16 * K;
  char* ldsA = smem + (w << 11);           // wave's chunk pair base
  char* ldsB = smem + 65536 + (w << 11);

  // fragment read addressing (swizzle applied on read)
  const int colRs = ((l >> 4) << 4) ^ (((l >> 3) & 1) << 5);
  const char* aRd = smem + (wm * 128 + (l & 15)) * 64 + colRs;
  const char* bRd = smem + 65536 + (wn * 64 + (l & 15)) * 64 + colRs;

  f32x4_t acc[8][4];
#pragma unroll
  for (int i = 0; i < 8; ++i)
#pragma unroll
    for (int j = 0; j < 4; ++j) acc[i][j] = f32x4_t{0.f, 0.f, 0.f, 0.f};

  bf16x8_t af[8], bfr[4];

#define STAGE_S(t) do { \
    const int sl_ = ((t) & 3) << 14; \
    gload_lds16(aS0 + (size_t)(t) * 32, ldsA + sl_); \
    gload_lds16(aS1 + (size_t)(t) * 32, ldsA + sl_ + 1024); \
    gload_lds16(bS0 + (size_t)(t) * 32, ldsB + sl_); \
    gload_lds16(bS1 + (size_t)(t) * 32, ldsB + sl_ + 1024); } while(0)

#define READ_S(s) do { \
    _Pragma("unroll") for (int n_ = 0; n_ < 4; ++n_) \
      bfr[n_] = *(const bf16x8_t*)(bRd + (s) * 16384 + n_ * 1024); \
    _Pragma("unroll") for (int m_ = 0; m_ < 8; ++m_) \
      af[m_] = *(const bf16x8_t*)(aRd + (s) * 16384 + m_ * 1024); } while(0)

#define MFMA32() do { \
    __builtin_amdgcn_s_setprio(1); \
    _Pragma("unroll") for (int m_ = 0; m_ < 8; ++m_) \
      _Pragma("unroll") for (int n_ = 0; n_ < 4; ++n_) \
        acc[m_][n_] = __builtin_amdgcn_mfma_f32_16x16x32_bf16( \
            af[m_], bfr[n_], acc[m_][n_], 0, 0, 0); \
    __builtin_amdgcn_s_setprio(0); } while(0)

// one 32-k step: slab s static (0..3); stage slab t if DOST
#define STEP(s, vmn, DOST, t) do { \
    WAITVM(vmn); BARX(); \
    if (DOST) STAGE_S(t); \
    READ_S(s); \
    LGKM0(); \
    MFMA32(); } while(0)

  // prologue: stage slabs 0,1,2 (12 loads)
  STAGE_S(0); STAGE_S(1); STAGE_S(2);

#pragma unroll 1
  for (int i = 0; i < NT - 4; i += 4) {
    STEP(0, 8, true, i + 3);
    STEP(1, 8, true, i + 4);
    STEP(2, 8, true, i + 5);
    STEP(3, 8, true, i + 6);
  }
  // peel: steps NT-4 .. NT-1 (slabs 0,1,2,3 since NT%4==0)
  STEP(0, 8, true, NT - 1);
  STEP(1, 8, false, 0);
  STEP(2, 4, false, 0);
  STEP(3, 0, false, 0);

  // ---------------- epilogue ----------------
  // C/D layout: col = lane&15, row = (lane>>4)*4 + reg (m89-verified)
  const int colBase = tileN + wn * 64 + (l & 15);
  float bv[4];
  bv[0] = bias[colBase];      bv[1] = bias[colBase + 16];
  bv[2] = bias[colBase + 32]; bv[3] = bias[colBase + 48];

  if constexpr (EPI == 0) {
    u16* C = (u16*)Cout;
    const int rowB = tileM + wm * 128 + ((l >> 4) << 2);
#pragma unroll
    for (int m = 0; m < 8; ++m)
#pragma unroll
      for (int nn = 0; nn < 4; ++nn)
#pragma unroll
        for (int j = 0; j < 4; ++j) {
          float v = acc[m][nn][j] + bv[nn];
          float t = 1.7159f * fast_tanh(0.666f * v);
          C[(size_t)(rowB + m * 16 + j) * NI + colBase + nn * 16] = f2bf(t);
        }
  } else {
    // heads interleaved per 16-col block: nn == head
    const int hg = ((tileN + wn * 64) >> 6) * 16 + (l & 15);
    float* out = (float*)Cout;
#pragma unroll
    for (int m = 0; m < 8; ++m)
#pragma unroll
      for (int j = 0; j < 4; ++j) {
        const int rl = wm * 128 + m * 16 + ((l >> 4) << 2) + j;
        const float tsv = ts[tileM + rl];   // L1 broadcast hit
        float ff1 = fast_tanh(acc[m][0][j] + bv[0]);
        float ff2 = fast_tanh(acc[m][1][j] + bv[1]);
        float s = fast_sigmoid((acc[m][2][j] + bv[2]) * tsv + (acc[m][3][j] + bv[3]));
        out[(size_t)(tileM + rl) * 512 + hg] = ff1 + s * (ff2 - ff1);
      }
  }
#undef STAGE_S
#undef READ_S
#undef MFMA32
#undef STEP
}

// ---------------- launch ----------------

extern "C" void kernel_launch(void* const* d_in, const int* in_sizes, int n_in,
                              void* d_out, int out_size, void* d_ws, size_t ws_size,
                              hipStream_t stream) {
  const float* input = (const float*)d_in[0];
  const float* hx    = (const float*)d_in[1];
  const float* ts    = (const float*)d_in[2];
  const float* W0    = (const float*)d_in[3];
  const float* b0    = (const float*)d_in[4];
  const float* W1    = (const float*)d_in[5];
  const float* b1    = (const float*)d_in[6];
  const float* Wff1  = (const float*)d_in[7];
  const float* bff1  = (const float*)d_in[8];
  const float* Wff2  = (const float*)d_in[9];
  const float* bff2  = (const float*)d_in[10];
  const float* Wta   = (const float*)d_in[11];
  const float* bta   = (const float*)d_in[12];
  const float* Wtb   = (const float*)d_in[13];
  const float* btb   = (const float*)d_in[14];

  const size_t WS_NEEDED = 544743424ull;
  if (ws_size < WS_NEEDED) return;
  char* ws = (char*)d_ws;
  u16* Xcat = (u16*)(ws);                      // [M,768] bf16, reused as X2 [M,1024]
  u16* X2   = (u16*)(ws);
  u16* X1   = (u16*)(ws + 268435456ull);       // [M,1024] bf16
  u16* W0T  = (u16*)(ws + 536870912ull);       // [1024][768]
  u16* W1T  = (u16*)(ws + 538443776ull);       // [1024][1024]
  u16* WhT  = (u16*)(ws + 540540928ull);       // [2048][1024] head-interleaved
  float* biasi = (float*)(ws + 544735232ull);  // [2048]

  prep_x<<<2048, 256, 0, stream>>>(input, hx, Xcat);
  prep_w<<<1922, 256, 0, stream>>>(W0, W1, Wff1, Wff2, Wta, Wtb,
                                   bff1, bff2, bta, btb, W0T, W1T, WhT, biasi);

  gemm256<768, 1024, 0><<<2048, 512, 0, stream>>>(Xcat, W0T, b0, nullptr, X1);
  gemm256<1024, 1024, 0><<<2048, 512, 0, stream>>>(X1, W1T, b1, nullptr, X2);
  gemm256<1024, 2048, 1><<<4096, 512, 0, stream>>>(X2, WhT, biasi, ts, d_out);
}